// Round 7
// baseline (428.538 us; speedup 1.0000x reference)
//
#include <hip/hip_runtime.h>

// DeformConvBlock B=4,C=64,H=W=256,OUT=64 — fp16 MFMA pipeline.
// R13: phase-1 offload. R6 tell: pipeline became real (VGPR 108) but traded
// occupancy 1:1 (occ 20%) -> only 3us. Gap ledger across 6 K1 designs
// (96-113us) says fixed overhead ~85us + small K1 -> stop touching K1/total.
// Lever: deform_main held the offset conv (25-30% of its loads, 24+ regs of
// state) hostage at 2 blocks/CU. Now:
//  * K1b offsets_conv: standalone dense conv at full occupancy (VGPR ~60,
//    8 waves/SIMD self-hides latency), writes [row][px][18] f32 (+bias).
//  * K2: phase 1 replaced by coalesced 9KB LDS fill of its offset window;
//    acc1/st1/v1 freed -> launch_bounds(256,4); phase-2 pipeline unchanged.

typedef _Float16 half8 __attribute__((ext_vector_type(8)));
typedef _Float16 h2    __attribute__((ext_vector_type(2)));
typedef float floatx4  __attribute__((ext_vector_type(4)));

namespace {
constexpr int B_ = 4, C_ = 64, H_ = 256, W_ = 256, OUT_ = 64;
constexpr int HW_ = H_ * W_;
constexpr size_t XT_BYTES = (size_t)B_ * HW_ * C_ * 2;      // 32 MB plane-major f16
constexpr size_t WOFF_OFF = XT_BYTES;                        // [9][2][2][64][8] f16
constexpr int    WOFF_N   = 9 * 2 * 2 * 64 * 8;
constexpr size_t WDEF_OFF = WOFF_OFF + (size_t)WOFF_N * 2;   // [9][2][4][64][8] f16
constexpr int    WDEF_N   = 9 * 2 * 4 * 64 * 8;
constexpr size_t OFFG_OFF = WDEF_OFF + (size_t)WDEF_N * 2;   // [B*H][W][18] f32
// xt granule index: (((b*256 + y)*8 + kcq)*256 + px), each granule = 8 f16 = 16B
}

// ------- K1: x CHW f32 -> plane-major f16 (+ weight prep in first 32 blocks) -
__global__ __launch_bounds__(256)
void transpose_x(const float* __restrict__ x, _Float16* __restrict__ xt,
                 const float* __restrict__ w_off, const float* __restrict__ w_def,
                 _Float16* __restrict__ wof, _Float16* __restrict__ wdf)
{
    __shared__ float tile[64 * 132];
    const int bid = blockIdx.x;            // ((b*256 + y)*2 + half)
    const int half = bid & 1;
    const int row = bid >> 1;              // b*256 + y
    const int b = row >> 8, y = row & 255;
    const int t = threadIdx.x;
    const float* __restrict__ xp = x + (size_t)b * C_ * HW_ + y * W_ + half * 128;

#pragma unroll
    for (int i = 0; i < 8; ++i) {
        const int c = i * 8 + (t >> 5);        // 0..63
        const int px = (t & 31) * 4;           // 0..124
        const float4 v = *(const float4*)&xp[(size_t)c * HW_ + px];
        *(float4*)&tile[c * 132 + px] = v;
    }
    __syncthreads();

#pragma unroll
    for (int rr = 0; rr < 4; ++rr) {
        const int kcq = (t >> 7) * 4 + rr;     // 0..7
        const int px = t & 127;                // 0..127
        union { _Float16 h[8]; uint4 u; } g;
#pragma unroll
        for (int cc = 0; cc < 8; ++cc)
            g.h[cc] = (_Float16)tile[(kcq * 8 + cc) * 132 + px];
        *(uint4*)(xt + (((size_t)row * 8 + kcq) * 256 + half * 128 + px) * 8) = g.u;
    }

    // ---- weight prep (blocks 0..31): coalesced reads, scattered stores ----
    if (bid < 32) {
        const int i0 = bid * 256 + threadIdx.x;          // 0..8191
        for (int s = i0; s < OUT_ * C_ * 9; s += 8192) {  // wdf: 36864 elems
            const int n = s / 576;                        // 576 = 64*9
            const int r = s - n * 576;
            const int c = r / 9;
            const int tap = r - c * 9;
            const int idx = ((((tap * 2 + (c >> 5)) * 4 + (n >> 4)) * 64
                              + ((c >> 3) & 3) * 16 + (n & 15)) << 3) + (c & 7);
            wdf[idx] = (_Float16)w_def[s];
        }
        for (int s = i0; s < 18 * C_ * 9; s += 8192) {    // wof: 10368 elems
            const int n = s / 576;
            const int r = s - n * 576;
            const int c = r / 9;
            const int tap = r - c * 9;
            const int idx = ((((tap * 2 + (c >> 5)) * 2 + (n >> 4)) * 64
                              + ((c >> 3) & 3) * 16 + (n & 15)) << 3) + (c & 7);
            wof[idx] = (_Float16)w_off[s];
        }
        // zero padding slots (n = 16 + (lane&15) >= 18); disjoint from above
        for (int i = i0; i < WOFF_N; i += 8192) {
            const int lane = (i >> 3) & 63, nt = (i >> 9) & 1;
            if (nt == 1 && (lane & 15) >= 2) wof[i] = (_Float16)0.0f;
        }
    }
}

// ------- K1b: offset conv via MFMA, full occupancy, writes [row][px][18] ----
__global__ __launch_bounds__(256)
void offsets_conv(const _Float16* __restrict__ xt,
                  const _Float16* __restrict__ wof,
                  const float* __restrict__ b_off,
                  float* __restrict__ off_g)
{
    const int tid = threadIdx.x;
    const int lane = tid & 63;
    const int wv = tid >> 6;
    const int lm = lane & 15;
    const int lq = lane >> 4;
    const int bid = blockIdx.x;            // (b*256+y)*2 + half
    const int half = bid & 1;
    const int row = bid >> 1;
    const int b = row >> 8, y = row & 255;
    const int base = half * 128 + wv * 32; // this wave's 32-px window
    const _Float16* __restrict__ xtb = xt + (size_t)b * HW_ * C_;

    floatx4 acc1[2][2];
#pragma unroll
    for (int pt = 0; pt < 2; ++pt)
#pragma unroll
        for (int nt = 0; nt < 2; ++nt) acc1[pt][nt] = (floatx4)0.0f;

#pragma unroll
    for (int tap = 0; tap < 9; ++tap) {
        const int dy = tap / 3 - 1, dx = tap % 3 - 1;
        const int ys = y + dy;
        const bool yok = (unsigned)ys < 256u;
        const int ysc = min(max(ys, 0), 255);
#pragma unroll
        for (int kc = 0; kc < 2; ++kc) {
            half8 bfr[2];
#pragma unroll
            for (int nt = 0; nt < 2; ++nt)
                bfr[nt] = *(const half8*)(wof +
                    ((size_t)(((tap * 2 + kc) * 2 + nt) * 64 + lane)) * 8);
            const int plane = (kc * 4 + lq) * 256;
#pragma unroll
            for (int pt = 0; pt < 2; ++pt) {
                const int px_s = base + pt * 16 + lm + dx;
                const bool vld = yok && ((unsigned)px_s < 256u);
                const int pxc = min(max(px_s, 0), 255);
                uint4 t = *(const uint4*)(xtb +
                    ((size_t)(ysc * 2048 + plane + pxc)) * 8);
                if (!vld) { t.x = 0u; t.y = 0u; t.z = 0u; t.w = 0u; }
                const half8 afr = __builtin_bit_cast(half8, t);
#pragma unroll
                for (int nt = 0; nt < 2; ++nt)
                    acc1[pt][nt] = __builtin_amdgcn_mfma_f32_16x16x32_f16(
                        afr, bfr[nt], acc1[pt][nt], 0, 0, 0);
            }
        }
    }

#pragma unroll
    for (int nt = 0; nt < 2; ++nt) {
        const int j = nt * 16 + lm;
        if (j < 18) {
            const float bj = b_off[j];
#pragma unroll
            for (int pt = 0; pt < 2; ++pt) {
#pragma unroll
                for (int r = 0; r < 4; ++r) {
                    const int lpx = base + pt * 16 + lq * 4 + r;
                    off_g[((size_t)row * 256 + lpx) * 18 + j] = acc1[pt][nt][r] + bj;
                }
            }
        }
    }
}

// ---------------- K2 helpers ----------------
// a[i] = granule base (yc*2048 + xc); add (kc*4+lq)*256 for the channel plane.
__device__ __forceinline__ void bilin_setup(float ys, float xs, int* a, float* w)
{
    const float y0f = floorf(ys), x0f = floorf(xs);
    const float ly = ys - y0f, lx = xs - x0f;
    const int y0 = (int)y0f, x0 = (int)x0f;
    const int y1 = y0 + 1, x1 = x0 + 1;
    const int y0c = min(max(y0, 0), H_ - 1);
    const int y1c = min(max(y1, 0), H_ - 1);
    const int x0c = min(max(x0, 0), W_ - 1);
    const int x1c = min(max(x1, 0), W_ - 1);
    const float fy0 = (y0 >= 0 && y0 < H_) ? 1.0f : 0.0f;
    const float fy1 = (y1 >= 0 && y1 < H_) ? 1.0f : 0.0f;
    const float fx0 = (x0 >= 0 && x0 < W_) ? 1.0f : 0.0f;
    const float fx1 = (x1 >= 0 && x1 < W_) ? 1.0f : 0.0f;
    a[0] = y0c * 2048 + x0c;  w[0] = (1.0f - ly) * (1.0f - lx) * fy0 * fx0;
    a[1] = y0c * 2048 + x1c;  w[1] = (1.0f - ly) * lx          * fy0 * fx1;
    a[2] = y1c * 2048 + x0c;  w[2] = ly          * (1.0f - lx) * fy1 * fx0;
    a[3] = y1c * 2048 + x1c;  w[3] = ly          * lx          * fy1 * fx1;
}

// ---------------- K2: deform gather + MFMA, pipelined (phase-2 only) --------
__global__ __launch_bounds__(256, 4)
void deform_main(const _Float16* __restrict__ xt,
                 const float* __restrict__ off_g,
                 const _Float16* __restrict__ wdf,
                 const float* __restrict__ b_def,
                 float* __restrict__ out)
{
    __shared__ float off_lds[128 * 18];       // offsets (4 rows x 32 px)

    const int tid = threadIdx.x;
    const int lane = tid & 63;
    const int wv = tid >> 6;            // wave id: row y0+wv
    const int lm = lane & 15;
    const int lq = lane >> 4;
    const int bid = blockIdx.x;                      // 2048
    const int uid = (bid & 7) * 256 + (bid >> 3);    // XCD band swizzle
    const int colc = uid & 7;
    const int rowg = (uid >> 3) & 63;
    const int b = uid >> 9;
    const int y0 = rowg * 4;
    const int y = y0 + wv;                           // this wave's row
    const int base = colc * 32;                      // px window [base, base+32)
    const _Float16* __restrict__ xtb = xt + (size_t)b * HW_ * C_;

    // ---- fill off_lds: rows y0..y0+3, px [base, base+32), 18 f32/px ----
    {
        const int r = tid >> 6;          // 0..3
        const int t64 = tid & 63;
        const float* __restrict__ src =
            off_g + ((size_t)(((b << 8) + y0 + r) * 256 + base)) * 18;
#pragma unroll
        for (int k = 0; k < 9; ++k)
            off_lds[r * 576 + t64 * 9 + k] = src[t64 * 9 + k];
    }
    __syncthreads();   // the ONLY barrier

    // ================= phase 2: pipelined gather + MFMA =====================
    floatx4 acc[2][4];
#pragma unroll
    for (int pt = 0; pt < 2; ++pt)
#pragma unroll
        for (int ot = 0; ot < 4; ++ot) acc[pt][ot] = (floatx4)0.0f;

    int   ca2[2][2][4];   // [tap parity][pt][corner] granule bases
    h2    cw2[2][2][4];   // [tap parity][pt][corner] f16 blend weights
    uint4 stc[2][2][4];   // [group parity][pt][corner] staged corner data

#define P2_BILIN(TAP, TP) do {                                               \
        const int ki_ = (TAP) / 3, kj_ = (TAP) % 3;                          \
        _Pragma("unroll")                                                    \
        for (int pt_ = 0; pt_ < 2; ++pt_) {                                  \
            const int lpx_ = wv * 32 + pt_ * 16 + lm;                        \
            const float2 o2_ = *(const float2*)&off_lds[lpx_ * 18 + (TAP) * 2]; \
            const float ys_ = (float)(y + ki_ - 1) + o2_.x;                  \
            const float xs_ = (float)(base + pt_ * 16 + lm + kj_ - 1) + o2_.y; \
            float cwf_[4];                                                   \
            bilin_setup(ys_, xs_, ca2[TP][pt_], cwf_);                       \
            _Pragma("unroll")                                                \
            for (int c_ = 0; c_ < 4; ++c_)                                   \
                cw2[TP][pt_][c_] = (h2)((_Float16)cwf_[c_]);                 \
        } } while (0)

#define P2_ISSUE(TP, KC, PAR) do {                                           \
        const int plane_ = ((KC) * 4 + lq) * 256;                            \
        _Pragma("unroll")                                                    \
        for (int pt_ = 0; pt_ < 2; ++pt_)                                    \
            _Pragma("unroll")                                                \
            for (int c_ = 0; c_ < 4; ++c_)                                   \
                stc[PAR][pt_][c_] = *(const uint4*)(xtb +                    \
                    (size_t)(ca2[TP][pt_][c_] + plane_) * 8);                \
        } while (0)

    P2_BILIN(0, 0);
    P2_ISSUE(0, 0, 0);
    __builtin_amdgcn_sched_barrier(0);

#pragma unroll
    for (int g = 0; g < 18; ++g) {
        const int tap = g >> 1, kc = g & 1, par = g & 1, tp = (g >> 1) & 1;

        // issue next group's gathers before consuming this one; pin them high
        if (kc == 0) {
            P2_ISSUE(tp, 1, 1);
            __builtin_amdgcn_sched_barrier(0);
        } else if (tap < 8) {
            P2_ISSUE(tp ^ 1, 0, 0);     // uses bilin computed last even step
            __builtin_amdgcn_sched_barrier(0);
        }

        half8 bfr[4];
#pragma unroll
        for (int ot = 0; ot < 4; ++ot)
            bfr[ot] = *(const half8*)(wdf +
                ((size_t)(((tap * 2 + kc) * 4 + ot) * 64 + lane)) * 8);

        // next tap's bilin VALU runs under the in-flight loads
        if (kc == 0 && tap < 8) P2_BILIN(tap + 1, tp ^ 1);

#pragma unroll
        for (int pt = 0; pt < 2; ++pt) {
            union Uc { uint4 u; h2 p[4]; } cc0, cc1, cc2, cc3;
            cc0.u = stc[par][pt][0];
            cc1.u = stc[par][pt][1];
            cc2.u = stc[par][pt][2];
            cc3.u = stc[par][pt][3];
            union Rr { h2 s[4]; half8 v; } r;
#pragma unroll
            for (int k = 0; k < 4; ++k)
                r.s[k] = cw2[tp][pt][0] * cc0.p[k] + cw2[tp][pt][1] * cc1.p[k]
                       + cw2[tp][pt][2] * cc2.p[k] + cw2[tp][pt][3] * cc3.p[k];
#pragma unroll
            for (int ot = 0; ot < 4; ++ot)
                acc[pt][ot] = __builtin_amdgcn_mfma_f32_16x16x32_f16(
                    r.v, bfr[ot], acc[pt][ot], 0, 0, 0);
        }
    }
#undef P2_BILIN
#undef P2_ISSUE

    // ================= epilogue: float4 stores =================
#pragma unroll
    for (int ot = 0; ot < 4; ++ot) {
        const int o = ot * 16 + lm;
        const float bd = b_def[o];
#pragma unroll
        for (int pt = 0; pt < 2; ++pt) {
            const int pxs = base + pt * 16 + lq * 4;
            const floatx4 a = acc[pt][ot];
            float4 v = make_float4(a[0] + bd, a[1] + bd, a[2] + bd, a[3] + bd);
            *(float4*)&out[(((size_t)b * OUT_ + o) * H_ + y) * W_ + pxs] = v;
        }
    }
}

extern "C" void kernel_launch(void* const* d_in, const int* in_sizes, int n_in,
                              void* d_out, int out_size, void* d_ws, size_t ws_size,
                              hipStream_t stream)
{
    const float* x     = (const float*)d_in[0];
    const float* w_off = (const float*)d_in[1];
    const float* b_off = (const float*)d_in[2];
    const float* w_def = (const float*)d_in[3];
    const float* b_def = (const float*)d_in[4];
    float* out = (float*)d_out;

    _Float16* xt  = (_Float16*)d_ws;
    _Float16* wof = (_Float16*)((char*)d_ws + WOFF_OFF);
    _Float16* wdf = (_Float16*)((char*)d_ws + WDEF_OFF);
    float*    offg = (float*)((char*)d_ws + OFFG_OFF);

    transpose_x<<<dim3(B_ * H_ * 2), dim3(256), 0, stream>>>(
        x, xt, w_off, w_def, wof, wdf);
    offsets_conv<<<dim3(B_ * H_ * 2), dim3(256), 0, stream>>>(
        xt, wof, b_off, offg);
    deform_main<<<dim3(B_ * H_ * 2), dim3(256), 0, stream>>>(
        xt, offg, wdf, b_def, out);
}